// Round 10
// baseline (677.467 us; speedup 1.0000x reference)
//
#include <hip/hip_runtime.h>

#define T_LEN 1024
#define HID   32
#define LDIM  16
#define BATCH 512
#define NB    16             // batch elems per block (MFMA N)
#define NT    192            // 3 waves: one per layer
#define U     4              // timesteps per phase
#define NPH   (256 + 2)      // phases p = 0..257
#define ROWB  80             // bytes per n-row in handoff buffer (64 data + 16 pad)
#define SLOTB (16 * ROWB)    // one t-slot: 1280 B
#define NSLOT 8              // t mod 8 slots (disjoint read/write halves)
#define LAYB  (NSLOT * SLOTB)
#define LOG2E 1.44269504f

typedef _Float16 half8  __attribute__((ext_vector_type(8)));
typedef _Float16 half2v __attribute__((ext_vector_type(2)));
typedef float    f32x4  __attribute__((ext_vector_type(4)));
typedef unsigned u32;
typedef unsigned u32x4  __attribute__((ext_vector_type(4)));

#if defined(__has_builtin)
#if __has_builtin(__builtin_amdgcn_rcpf)
#define FAST_RCP(x) __builtin_amdgcn_rcpf(x)
#endif
#if __has_builtin(__builtin_amdgcn_exp2f)
#define FAST_EXP2(x) __builtin_amdgcn_exp2f(x)
#endif
#if __has_builtin(__builtin_amdgcn_cvt_pkrtz)
#define PKRTZ(a, b) __builtin_bit_cast(u32, __builtin_amdgcn_cvt_pkrtz((a), (b)))
#endif
#endif
#ifndef FAST_RCP
#define FAST_RCP(x) (1.0f / (x))
#endif
#ifndef FAST_EXP2
#define FAST_EXP2(x) __expf(0.69314718f * (x))
#endif
#ifndef PKRTZ
static __device__ __forceinline__ u32 pkrtz_fallback(float a, float b) {
    half2v v; v[0] = (_Float16)a; v[1] = (_Float16)b;
    return __builtin_bit_cast(u32, v);
}
#define PKRTZ(a, b) pkrtz_fallback((a), (b))
#endif

#define MFMA(a, b, c) __builtin_amdgcn_mfma_f32_16x16x32_f16((a), (b), (c), 0, 0, 0)

__global__ __launch_bounds__(NT, 1)
void lstm_encoder_kernel(const float* __restrict__ x,
                         const float* __restrict__ Wih0, const float* __restrict__ Whh0,
                         const float* __restrict__ bih0, const float* __restrict__ bhh0,
                         const float* __restrict__ Wih1, const float* __restrict__ Whh1,
                         const float* __restrict__ bih1, const float* __restrict__ bhh1,
                         const float* __restrict__ Wih2, const float* __restrict__ Whh2,
                         const float* __restrict__ bih2, const float* __restrict__ bhh2,
                         const float* __restrict__ Wm,  const float* __restrict__ bm,
                         const float* __restrict__ Wlv, const float* __restrict__ blv,
                         float* __restrict__ out)
{
    const int b0   = blockIdx.x * NB;
    const int tid  = threadIdx.x;
    const int lane = tid & 63;
    const int l    = tid >> 6;        // wave index = layer 0..2
    const int n    = lane & 15;       // B/D column (batch) and A row-within-tile
    const int kc   = lane >> 4;       // k-group (A/B) and D row-quad

    __shared__ u32 xs[T_LEN * NB];                          // 64 KB packed f16 x pairs [t][n]
    __shared__ __align__(16) unsigned char hnd[2 * LAYB];   // handoff: layers 0,1 (20.5 KB)
    __shared__ float cbuf[NB * HID];

    // ---- stage all x into LDS as f16 pairs (coalesced) ----
    for (int i = tid; i < NB * T_LEN; i += NT) {
        const int nn = i >> 10, t = i & (T_LEN - 1);
        const float2 v = *(const float2*)(x + ((size_t)(b0 + nn) * T_LEN + t) * 2);
        half2v p; p[0] = (_Float16)v.x; p[1] = (_Float16)v.y;
        xs[t * NB + nn] = __builtin_bit_cast(u32, p);
    }
    // ---- zero handoff ----
    for (int i = tid; i < (int)(2 * LAYB / 4); i += NT) ((u32*)hnd)[i] = 0u;

    // ---- A fragments + bias, exp2-prescaled ----
    // Tile tau = role*2 + half (role 0..3 = i,f,g,o torch rows role*32+unit).
    // Tile-row m maps to unit(half,m) = 8*(m>>2) + 4*half + (m&3)  ==> D output
    // lane (n,kc) holds units 8kc..8kc+7, exactly the B k-slots it feeds next step.
    const float* Wih = (l == 0) ? Wih0 : (l == 1) ? Wih1 : Wih2;
    const float* Whh = (l == 0) ? Whh0 : (l == 1) ? Whh1 : Whh2;
    const float* bih = (l == 0) ? bih0 : (l == 1) ? bih1 : bih2;
    const float* bhh = (l == 0) ? bhh0 : (l == 1) ? bhh1 : bhh2;

    half8 aself[8], aprev[8];
    f32x4 biasC[8];
#pragma unroll
    for (int tau = 0; tau < 8; ++tau) {
        const int   role = tau >> 1, half = tau & 1;
        const float sc   = (role == 2) ? (2.0f * LOG2E) : LOG2E;
        const int   R_A  = role * 32 + 8 * (n >> 2) + 4 * half + (n & 3);  // A row for this lane
#pragma unroll
        for (int i2 = 0; i2 < 8; ++i2) {
            const int kk = kc * 8 + i2;
            aself[tau][i2] = (_Float16)(Whh[R_A * HID + kk] * sc);
            aprev[tau][i2] = (_Float16)(((l == 0) ? ((kk < 2) ? Wih[R_A * 2 + kk] : 0.0f)
                                                  : Wih[R_A * HID + kk]) * sc);
        }
#pragma unroll
        for (int r = 0; r < 4; ++r) {
            const int R_D = role * 32 + 8 * kc + 4 * half + r;  // D row m = kc*4+r
            biasC[tau][r] = (bih[R_D] + bhh[R_D]) * sc;
        }
    }

    u32x4 hB = {0u, 0u, 0u, 0u};                      // self B-frag: h_l(t-1), lane-local
    float cc[8] = {0.f, 0.f, 0.f, 0.f, 0.f, 0.f, 0.f, 0.f};

    __syncthreads();

    for (int p = 0; p < NPH; ++p) {
        if ((unsigned)(p - l) < 256u) {
            const int t0 = 4 * (p - l);
            // ---- phase-start prev-chunk loads (issue all 4, wait once) ----
            u32x4 pb[U];
            if (l == 0) {
#pragma unroll
                for (int u = 0; u < U; ++u) {
                    const u32 xw = xs[(t0 + u) * NB + n];       // broadcast across kc copies
                    pb[u][0] = (kc == 0) ? xw : 0u;
                    pb[u][1] = 0u; pb[u][2] = 0u; pb[u][3] = 0u;
                }
            } else {
#pragma unroll
                for (int u = 0; u < U; ++u)
                    pb[u] = *(const u32x4*)(hnd + (l - 1) * LAYB +
                                            ((t0 + u) & 7) * SLOTB + n * ROWB + kc * 16);
            }
#pragma unroll
            for (int u = 0; u < U; ++u) {
                f32x4 acc[8];
#pragma unroll
                for (int tau = 0; tau < 8; ++tau)   // off-chain: prev contribution + bias
                    acc[tau] = MFMA(aprev[tau], __builtin_bit_cast(half8, pb[u]), biasC[tau]);
#pragma unroll
                for (int tau = 0; tau < 8; ++tau)   // on-chain: self recurrence
                    acc[tau] = MFMA(aself[tau], __builtin_bit_cast(half8, hB), acc[tau]);

                float hv[8];
#pragma unroll
                for (int uu = 0; uu < 8; ++uu) {
                    const int hh = uu >> 2, r = uu & 3;
                    const float ei = FAST_EXP2(-acc[0 + hh][r]);   // i (log2e-scaled)
                    const float ef = FAST_EXP2(-acc[2 + hh][r]);   // f
                    const float eg = FAST_EXP2(-acc[4 + hh][r]);   // g (2log2e-scaled)
                    const float eo = FAST_EXP2(-acc[6 + hh][r]);   // o
                    const float ig = (1.0f - eg) * FAST_RCP((1.0f + ei) * (1.0f + eg));
                    const float fv = FAST_RCP(1.0f + ef);
                    float c_ = fmaf(fv, cc[uu], ig);
                    c_ = fminf(fmaxf(c_, -20.0f), 20.0f);
                    cc[uu] = c_;
                    const float ec = FAST_EXP2(-2.0f * LOG2E * c_);
                    hv[uu] = (1.0f - ec) * FAST_RCP((1.0f + eo) * (1.0f + ec));  // o*tanh(c)
                }
                u32x4 nh;
                nh[0] = PKRTZ(hv[0], hv[1]);
                nh[1] = PKRTZ(hv[2], hv[3]);
                nh[2] = PKRTZ(hv[4], hv[5]);
                nh[3] = PKRTZ(hv[6], hv[7]);
                hB = nh;                                          // lane-local self B-frag
                if (l < 2)                                        // handoff for layer l+1
                    *(u32x4*)(hnd + l * LAYB + ((t0 + u) & 7) * SLOTB + n * ROWB + kc * 16) = hB;
            }
        }
        __syncthreads();   // one barrier per 4 timesteps
    }

    // ---- final c3 of layer 2 -> LDS ----
    if (l == 2) {
#pragma unroll
        for (int uu = 0; uu < 8; ++uu) cbuf[n * HID + 8 * kc + uu] = cc[uu];
    }
    __syncthreads();

    // ---- projection: mean / log_var ----
    for (int v = tid; v < NB * 2 * LDIM; v += NT) {
        const int  nn = v >> 5;
        const int  o  = v & 31;
        const bool is_mean = (o < LDIM);
        const int  jo = o & (LDIM - 1);
        const float* W  = is_mean ? Wm : Wlv;
        float acc = is_mean ? bm[jo] : blv[jo];
#pragma unroll
        for (int k = 0; k < HID; ++k) acc = fmaf(W[jo * HID + k], cbuf[nn * HID + k], acc);
        out[(is_mean ? 0 : (size_t)BATCH * LDIM) + (size_t)(b0 + nn) * LDIM + jo] = acc;
    }
}

extern "C" void kernel_launch(void* const* d_in, const int* in_sizes, int n_in,
                              void* d_out, int out_size, void* d_ws, size_t ws_size,
                              hipStream_t stream) {
    const float* x    = (const float*)d_in[0];
    const float* Wih0 = (const float*)d_in[1];
    const float* Whh0 = (const float*)d_in[2];
    const float* bih0 = (const float*)d_in[3];
    const float* bhh0 = (const float*)d_in[4];
    const float* Wih1 = (const float*)d_in[5];
    const float* Whh1 = (const float*)d_in[6];
    const float* bih1 = (const float*)d_in[7];
    const float* bhh1 = (const float*)d_in[8];
    const float* Wih2 = (const float*)d_in[9];
    const float* Whh2 = (const float*)d_in[10];
    const float* bih2 = (const float*)d_in[11];
    const float* bhh2 = (const float*)d_in[12];
    const float* Wm   = (const float*)d_in[13];
    const float* bm   = (const float*)d_in[14];
    const float* Wlv  = (const float*)d_in[15];
    const float* blv  = (const float*)d_in[16];
    float* out = (float*)d_out;

    lstm_encoder_kernel<<<dim3(BATCH / NB), dim3(NT), 0, stream>>>(
        x, Wih0, Whh0, bih0, bhh0, Wih1, Whh1, bih1, bhh1,
        Wih2, Whh2, bih2, bhh2, Wm, bm, Wlv, blv, out);
}

// Round 11
// 519.579 us; speedup vs baseline: 1.3039x; 1.3039x over previous
//
#include <hip/hip_runtime.h>

#define T_LEN 1024
#define HID   32
#define LDIM  16
#define BATCH 512
#define NB    16             // batch elems per block (MFMA N)
#define NT    768            // 12 waves: 3 layers x 4 unit-groups
#define ROWB  80             // bytes per n-row (64 data + 16 pad)
#define SLOTB (16 * ROWB)    // one slot: 16 n-rows = 1280 B
#define PARB  (4 * SLOTB)    // slots: h0, h1, h2, x
#define LOG2E 1.44269504f

typedef _Float16 half8  __attribute__((ext_vector_type(8)));
typedef _Float16 half2v __attribute__((ext_vector_type(2)));
typedef float    f32x4  __attribute__((ext_vector_type(4)));
typedef unsigned u32;
typedef unsigned u32x4  __attribute__((ext_vector_type(4)));

#if defined(__has_builtin)
#if __has_builtin(__builtin_amdgcn_rcpf)
#define FAST_RCP(x) __builtin_amdgcn_rcpf(x)
#endif
#if __has_builtin(__builtin_amdgcn_exp2f)
#define FAST_EXP2(x) __builtin_amdgcn_exp2f(x)
#endif
#if __has_builtin(__builtin_amdgcn_cvt_pkrtz)
#define PKRTZ(a, b) __builtin_bit_cast(u32, __builtin_amdgcn_cvt_pkrtz((a), (b)))
#endif
#endif
#ifndef FAST_RCP
#define FAST_RCP(x) (1.0f / (x))
#endif
#ifndef FAST_EXP2
#define FAST_EXP2(x) __expf(0.69314718f * (x))
#endif
#ifndef PKRTZ
static __device__ __forceinline__ u32 pkrtz_fallback(float a, float b) {
    half2v v; v[0] = (_Float16)a; v[1] = (_Float16)b;
    return __builtin_bit_cast(u32, v);
}
#define PKRTZ(a, b) pkrtz_fallback((a), (b))
#endif

#define MFMA(a, b, c) __builtin_amdgcn_mfma_f32_16x16x32_f16((a), (b), (c), 0, 0, 0)

__global__ __launch_bounds__(NT, 1)
void lstm_encoder_kernel(const float* __restrict__ x,
                         const float* __restrict__ Wih0, const float* __restrict__ Whh0,
                         const float* __restrict__ bih0, const float* __restrict__ bhh0,
                         const float* __restrict__ Wih1, const float* __restrict__ Whh1,
                         const float* __restrict__ bih1, const float* __restrict__ bhh1,
                         const float* __restrict__ Wih2, const float* __restrict__ Whh2,
                         const float* __restrict__ bih2, const float* __restrict__ bhh2,
                         const float* __restrict__ Wm,  const float* __restrict__ bm,
                         const float* __restrict__ Wlv, const float* __restrict__ blv,
                         float* __restrict__ out)
{
    const int b0   = blockIdx.x * NB;
    const int tid  = threadIdx.x;
    const int lane = tid & 63;
    const int wave = tid >> 6;        // 0..11
    const int l    = wave >> 2;       // layer 0..2
    const int w    = wave & 3;        // unit-group: units 8w..8w+7
    const int n    = lane & 15;       // batch col / A row-within-tile
    const int kc   = lane >> 4;       // k-chunk / D row-quad

    __shared__ u32 xs[T_LEN * NB];                          // 64 KB packed f16 x pairs [t][n]
    __shared__ __align__(16) unsigned char hb[2 * PARB];    // 10 KB: parity x {h0,h1,h2,x}
    __shared__ float cbuf[NB * HID];

    // ---- stage all x into LDS as f16 pairs (coalesced) ----
    for (int i = tid; i < NB * T_LEN; i += NT) {
        const int nn = i >> 10, t = i & (T_LEN - 1);
        const float2 v = *(const float2*)(x + ((size_t)(b0 + nn) * T_LEN + t) * 2);
        half2v p; p[0] = (_Float16)v.x; p[1] = (_Float16)v.y;
        xs[t * NB + nn] = __builtin_bit_cast(u32, p);
    }
    for (int i = tid; i < (int)(2 * PARB / 4); i += NT) ((u32*)hb)[i] = 0u;

    // ---- A fragments + bias (role-pair packed tiles), exp2-prescaled ----
    // Tile tau0 packs roles (i,f), tau1 packs (g,o); tile-row m = 2*u_loc + rho.
    // Wave w owns units 8w..8w+7. D lane (n,kc) reg r -> (u_loc=2kc+(r>>1), rho=r&1)
    // => each lane holds 2 complete cells (all 4 gates).
    const float* Wih = (l == 0) ? Wih0 : (l == 1) ? Wih1 : Wih2;
    const float* Whh = (l == 0) ? Whh0 : (l == 1) ? Whh1 : Whh2;
    const float* bih = (l == 0) ? bih0 : (l == 1) ? bih1 : bih2;
    const float* bhh = (l == 0) ? bhh0 : (l == 1) ? bhh1 : bhh2;

    half8 aprev[2], aself[2];
    f32x4 biasC[2];
#pragma unroll
    for (int tau = 0; tau < 2; ++tau) {
        const int   rho  = n & 1, uloc = n >> 1;
        const int   base = (tau == 0) ? (rho ? 32 : 0) : (rho ? 96 : 64);
        const int   R    = base + 8 * w + uloc;                    // A row for this lane
        const float sc   = (tau == 1 && rho == 0) ? (2.0f * LOG2E) : LOG2E;  // g rows 2x
#pragma unroll
        for (int i2 = 0; i2 < 8; ++i2) {
            const int kk = kc * 8 + i2;
            aself[tau][i2] = (_Float16)(Whh[R * HID + kk] * sc);
            aprev[tau][i2] = (_Float16)(((l == 0) ? ((kk < 2) ? Wih[R * 2 + kk] : 0.0f)
                                                  : Wih[R * HID + kk]) * sc);
        }
#pragma unroll
        for (int r = 0; r < 4; ++r) {
            const int   rr    = r & 1, uD = 2 * kc + (r >> 1);
            const int   baseD = (tau == 0) ? (rr ? 32 : 0) : (rr ? 96 : 64);
            const int   RD    = baseD + 8 * w + uD;
            const float scD   = (tau == 1 && rr == 0) ? (2.0f * LOG2E) : LOG2E;
            biasC[tau][r] = (bih[RD] + bhh[RD]) * scD;
        }
    }

    // ---- LDS offsets ----
    const int slotA  = (l == 0) ? 3 : (l - 1);                  // chunk0 source
    const int off_r0 = slotA * SLOTB + n * ROWB + kc * 16;
    const int off_r1 = l * SLOTB + n * ROWB + kc * 16;          // chunk1 = own h
    const int off_w  = l * SLOTB + n * ROWB + (8 * w + 2 * kc) * 2;
    const int off_x  = 3 * SLOTB + lane * ROWB;                 // feeder row (lane<16)
    const bool xf    = (wave == 0) && (lane < 16);

    float cc0 = 0.0f, cc1 = 0.0f;

    __syncthreads();
    if (xf) *(u32*)(hb + off_x) = xs[lane];   // parity0 xslot <- x(0)
    __syncthreads();

#define CELL(ai, af_, ag, ao, CC, HOUT)                                          \
    do {                                                                         \
        const float ei = FAST_EXP2(-(ai));                                       \
        const float ef = FAST_EXP2(-(af_));                                      \
        const float eg = FAST_EXP2(-(ag));                                       \
        const float eo = FAST_EXP2(-(ao));                                       \
        const float p1  = (1.0f + ei) * (1.0f + eg);                             \
        const float den = p1 * (1.0f + ef);                                      \
        const float tmn = (1.0f - eg) * (1.0f + ef);                             \
        float c_ = fmaf(CC, p1, tmn) * FAST_RCP(den);                            \
        c_ = fminf(fmaxf(c_, -20.0f), 20.0f);                                    \
        CC = c_;                                                                 \
        const float ec = FAST_EXP2(-2.0f * LOG2E * c_);                          \
        HOUT = (1.0f - ec) * FAST_RCP((1.0f + eo) * (1.0f + ec));                \
    } while (0)

#define STEP(P, S)                                                               \
    do {                                                                         \
        if ((unsigned)((S) - l) < (unsigned)T_LEN) {                             \
            u32 xw = 0;                                                          \
            if (xf) {                                                            \
                const int tn = ((S) + 1 < T_LEN) ? (S) + 1 : T_LEN - 1;          \
                xw = xs[tn * NB + lane];                                         \
            }                                                                    \
            const half8 bf0 = __builtin_bit_cast(half8,                          \
                *(const u32x4*)(hb + (P) * PARB + off_r0));                      \
            const half8 bf1 = __builtin_bit_cast(half8,                          \
                *(const u32x4*)(hb + (P) * PARB + off_r1));                      \
            f32x4 ac0 = MFMA(aprev[0], bf0, biasC[0]);                           \
            f32x4 ac1 = MFMA(aprev[1], bf0, biasC[1]);                           \
            ac0 = MFMA(aself[0], bf1, ac0);                                      \
            ac1 = MFMA(aself[1], bf1, ac1);                                      \
            float h0, h1;                                                        \
            CELL(ac0[0], ac0[1], ac1[0], ac1[1], cc0, h0);                       \
            CELL(ac0[2], ac0[3], ac1[2], ac1[3], cc1, h1);                       \
            *(u32*)(hb + ((P) ^ 1) * PARB + off_w) = PKRTZ(h0, h1);              \
            if (xf) *(u32*)(hb + ((P) ^ 1) * PARB + off_x) = xw;                 \
        }                                                                        \
        __syncthreads();                                                         \
    } while (0)

    for (int s = 0; s < T_LEN + 2; s += 2) {
        STEP(0, s);
        STEP(1, s + 1);
    }
#undef STEP
#undef CELL

    // ---- final c3 of layer 2 -> LDS ----
    if (l == 2) {
        cbuf[n * HID + 8 * w + 2 * kc + 0] = cc0;
        cbuf[n * HID + 8 * w + 2 * kc + 1] = cc1;
    }
    __syncthreads();

    // ---- projection: mean / log_var ----
    if (tid < NB * 2 * LDIM) {
        const int  nn = tid >> 5;
        const int  o  = tid & 31;
        const bool is_mean = (o < LDIM);
        const int  jo = o & (LDIM - 1);
        const float* W  = is_mean ? Wm : Wlv;
        float acc = is_mean ? bm[jo] : blv[jo];
#pragma unroll
        for (int k = 0; k < HID; ++k) acc = fmaf(W[jo * HID + k], cbuf[nn * HID + k], acc);
        out[(is_mean ? 0 : (size_t)BATCH * LDIM) + (size_t)(b0 + nn) * LDIM + jo] = acc;
    }
}

extern "C" void kernel_launch(void* const* d_in, const int* in_sizes, int n_in,
                              void* d_out, int out_size, void* d_ws, size_t ws_size,
                              hipStream_t stream) {
    const float* x    = (const float*)d_in[0];
    const float* Wih0 = (const float*)d_in[1];
    const float* Whh0 = (const float*)d_in[2];
    const float* bih0 = (const float*)d_in[3];
    const float* bhh0 = (const float*)d_in[4];
    const float* Wih1 = (const float*)d_in[5];
    const float* Whh1 = (const float*)d_in[6];
    const float* bih1 = (const float*)d_in[7];
    const float* bhh1 = (const float*)d_in[8];
    const float* Wih2 = (const float*)d_in[9];
    const float* Whh2 = (const float*)d_in[10];
    const float* bih2 = (const float*)d_in[11];
    const float* bhh2 = (const float*)d_in[12];
    const float* Wm   = (const float*)d_in[13];
    const float* bm   = (const float*)d_in[14];
    const float* Wlv  = (const float*)d_in[15];
    const float* blv  = (const float*)d_in[16];
    float* out = (float*)d_out;

    lstm_encoder_kernel<<<dim3(BATCH / NB), dim3(NT), 0, stream>>>(
        x, Wih0, Whh0, bih0, bhh0, Wih1, Whh1, bih1, bhh1,
        Wih2, Whh2, bih2, bhh2, Wm, bm, Wlv, blv, out);
}